// Round 2
// baseline (441.605 us; speedup 1.0000x reference)
//
#include <hip/hip_runtime.h>

#define VDIM 20000
#define EDIM 128
#define BATCH 64
#define SEQ 100
#define BN 96
#define NVT 209   // ceil(20000/96)
#define AROWS 112
#define ATILE (AROWS * EDIM)   // 14336 shorts = 28 KB

typedef float f32x4 __attribute__((ext_vector_type(4)));
typedef short bf16x8 __attribute__((ext_vector_type(8)));
typedef unsigned short ushortx8 __attribute__((ext_vector_type(8)));

typedef __attribute__((address_space(1))) const unsigned int gas_u32;
typedef __attribute__((address_space(3))) unsigned int las_u32;

__device__ __forceinline__ void async16(unsigned short* lds, const unsigned short* g) {
  __builtin_amdgcn_global_load_lds((gas_u32*)g, (las_u32*)lds, 16, 0, 0);
}

__device__ __forceinline__ unsigned short f2bf(float f) {
  unsigned u = __builtin_bit_cast(unsigned, f);
  u += 0x7FFFu + ((u >> 16) & 1u);   // RTNE
  return (unsigned short)(u >> 16);
}

// ---- fused prep: W->bf16 (blocks 0..2499) + A gather PRE-SWIZZLED (2500..2627)
// A tiles are 112 rows now: 0..99 = W[attr], 100 = direct emb, 101..111 = zero.
__global__ void prep_kernel(const float* __restrict__ Wi, const float* __restrict__ Wu,
                            const int* __restrict__ attr_item, const int* __restrict__ attr_user,
                            const int* __restrict__ item_ids, const int* __restrict__ user_ids,
                            const float* __restrict__ item_emb, const float* __restrict__ user_emb,
                            unsigned short* __restrict__ wbf, unsigned short* __restrict__ abf) {
  const int bid = blockIdx.x, t = threadIdx.x;
  if (bid < 2500) {
    const int c = bid & 1;
    const float* src = c ? Wu : Wi;
    unsigned short* dst = wbf + (size_t)c * (VDIM * EDIM);
    const int i0 = ((bid >> 1) * 256 + t) * 8;
    float4 a = *(const float4*)(src + i0);
    float4 b = *(const float4*)(src + i0 + 4);
    ushortx8 o;
    o[0] = f2bf(a.x); o[1] = f2bf(a.y); o[2] = f2bf(a.z); o[3] = f2bf(a.w);
    o[4] = f2bf(b.x); o[5] = f2bf(b.y); o[6] = f2bf(b.z); o[7] = f2bf(b.w);
    *(ushortx8*)(dst + i0) = o;
  } else {
    const int g = bid - 2500;
    const int b = g & 63, c = g >> 6;
    const int r = t >> 1, h = t & 1;
    if (r >= AROWS) return;
    const int* ids = c ? attr_user : attr_item;
    const float* W = c ? Wu : Wi;
    const float* demb = c ? user_emb : item_emb;
    const int* dids = c ? user_ids : item_ids;
    unsigned short* dst = abf + (size_t)(c * BATCH + b) * ATILE;
    const float* src = nullptr;
    if (r < SEQ)       src = W + (size_t)ids[b * SEQ + r] * EDIM;
    else if (r == SEQ) src = demb + (size_t)dids[b] * EDIM;
    if (src) {
      #pragma unroll
      for (int k = 0; k < 8; ++k) {
        const int jj = h * 8 + k;
        const int j = jj ^ (r & 15);
        float4 a  = *(const float4*)(src + j * 8);
        float4 bb = *(const float4*)(src + j * 8 + 4);
        ushortx8 o;
        o[0] = f2bf(a.x);  o[1] = f2bf(a.y);  o[2] = f2bf(a.z);  o[3] = f2bf(a.w);
        o[4] = f2bf(bb.x); o[5] = f2bf(bb.y); o[6] = f2bf(bb.z); o[7] = f2bf(bb.w);
        *(ushortx8*)(dst + (r * 16 + jj) * 8) = o;
      }
    } else {
      ushortx8 z = {0, 0, 0, 0, 0, 0, 0, 0};
      #pragma unroll
      for (int k = 0; k < 8; ++k) *(ushortx8*)(dst + (r * 16 + h * 8 + k) * 8) = z;
    }
  }
}

// ---- main: 256 thr (4 waves: wm2 x wn2), tile 112 rows x 96 cols.
// wm0: rows 0..63 (mt0..3). wm1: rows 64..111 (mt0..2). breg 48 VGPR +
// acc 48 AGPR; wv computation moved OUT of the MFMA-live range (epilogue,
// tf read direct from global — L2-resident) so __launch_bounds__(256,4)
// can cap total regs at 128 => 4 waves/SIMD. LDS 37,152 B => 4 blocks/CU.
// CRITICAL: all register arrays statically indexed (runtime-indexed acc
// previously demoted to scratch).
__global__ __launch_bounds__(256, 4)
void main_kernel(const unsigned short* __restrict__ wbf, const unsigned short* __restrict__ abf,
                 const float* __restrict__ tf_item, const int* __restrict__ lens_item,
                 const float* __restrict__ tf_user, const int* __restrict__ lens_user,
                 float* __restrict__ out) {
  __shared__ __align__(16) unsigned short sA[ATILE];   // 28 KB swizzled A tile
  __shared__ float sDen[2][2][BN];                     // [parity][wm][col]
  __shared__ float sNum[2][2][BN];
  __shared__ float sDir[2][BN];
  __shared__ float sRes[4][BN];
  __shared__ int   sLen[2][4];

  const int t = threadIdx.x;
  const int v0 = blockIdx.x * BN;          // 209 v-tiles
  const int bg4 = blockIdx.y * 4;          // 16 b-groups
  const int lane = t & 63, wave = t >> 6;
  const int wm = wave >> 1, wn = wave & 1;
  const int quad = lane >> 4, l15 = lane & 15;

  if (t < 8) sLen[t >> 2][t & 3] = ((t >= 4) ? lens_user : lens_item)[bg4 + (t & 3)];

  // ---- B fragments for cluster 0 (48 VGPRs) ----
  bf16x8 breg[3][4];
  #pragma unroll
  for (int nt = 0; nt < 3; ++nt) {
    const int v = v0 + wn * 48 + nt * 16 + l15;
    const unsigned short* p = wbf + (size_t)v * EDIM + quad * 8;
    const bool ok = (v < VDIM);
    #pragma unroll
    for (int ks = 0; ks < 4; ++ks) {
      bf16x8 z = {0, 0, 0, 0, 0, 0, 0, 0};
      breg[nt][ks] = ok ? *(const bf16x8*)(p + ks * 32) : z;
    }
  }

  // ---- issue async A DMA for stage 0 ----
  {
    const unsigned short* gb = abf + (size_t)bg4 * ATILE;
    #pragma unroll
    for (int i = 0; i < 7; ++i)
      async16(&sA[(i * 256 + wave * 64) * 8], gb + (size_t)(i * 256 + t) * 8);
  }

  #pragma unroll 1
  for (int s = 0; s < 8; ++s) {
    const int c = s >> 2, it = s & 3, buf = s & 1;

    __syncthreads();   // #1: DMA drained (sA = tile s); prev partials visible

    // ---- combine previous stage's partials (t<96 owns col t) ----
    if (s > 0 && t < BN) {
      const int ps = s - 1, p = ps & 1, pit = ps & 3;
      float den = sDen[p][0][t] + sDen[p][1][t];
      float num = sNum[p][0][t] + sNum[p][1][t];
      const float dir = sDir[p][t];
      den -= 11.f + __expf(dir);                 // 11 pad rows (101..111) + dir row
      const float val = num * __builtin_amdgcn_rcpf(den) + dir;
      if (ps < 4) sRes[pit][t] = val;
      else {
        const int v = v0 + t;
        if (v < VDIM) out[(size_t)(bg4 + pit) * VDIM + v] = sRes[pit][t] + val;
      }
    }

    // ---- GEMM: 16x16x32 tiles; A from LDS (swizzled), B from regs ----
    f32x4 acc[4][3];
    #pragma unroll
    for (int mt = 0; mt < 4; ++mt)
      #pragma unroll
      for (int nt = 0; nt < 3; ++nt) { f32x4 z = {0.f, 0.f, 0.f, 0.f}; acc[mt][nt] = z; }

    const unsigned char* pA = (const unsigned char*)&sA[0];
    #pragma unroll
    for (int ks = 0; ks < 4; ++ks) {
      const int j = ks * 4 + quad;
      const int sw = ((j ^ l15) << 4);
      bf16x8 af[3];
      #pragma unroll
      for (int mt = 0; mt < 3; ++mt)
        af[mt] = *(const bf16x8*)(pA + (wm * 64 + mt * 16 + l15) * 256 + sw);
      #pragma unroll
      for (int mt = 0; mt < 3; ++mt)
        #pragma unroll
        for (int nt = 0; nt < 3; ++nt)
          acc[mt][nt] = __builtin_amdgcn_mfma_f32_16x16x32_bf16(af[mt], breg[nt][ks], acc[mt][nt], 0, 0, 0);
      if (wm == 0) {   // wave-uniform; rows 48..63
        const bf16x8 a3 = *(const bf16x8*)(pA + (3 * 16 + l15) * 256 + sw);
        #pragma unroll
        for (int nt = 0; nt < 3; ++nt)
          acc[3][nt] = __builtin_amdgcn_mfma_f32_16x16x32_bf16(a3, breg[nt][ks], acc[3][nt], 0, 0, 0);
      }
    }

    __syncthreads();   // #2: all waves done reading sA (+ combine done)

    // ---- issue next stage's A DMA (covered by epilogue below) ----
    if (s < 7) {
      const int ns = s + 1;
      const unsigned short* gb = abf + (size_t)((ns >> 2) * BATCH + bg4 + (ns & 3)) * ATILE;
      #pragma unroll
      for (int i = 0; i < 7; ++i)
        async16(&sA[(i * 256 + wave * 64) * 8], gb + (size_t)(i * 256 + t) * 8);
    }
    // reload B for cluster 1 once
    if (s == 3) {
      const unsigned short* wb1 = wbf + (size_t)VDIM * EDIM;
      #pragma unroll
      for (int nt = 0; nt < 3; ++nt) {
        const int v = v0 + wn * 48 + nt * 16 + l15;
        const unsigned short* p = wb1 + (size_t)v * EDIM + quad * 8;
        const bool ok = (v < VDIM);
        #pragma unroll
        for (int ks = 0; ks < 4; ++ks) {
          bf16x8 z = {0, 0, 0, 0, 0, 0, 0, 0};
          breg[nt][ks] = ok ? *(const bf16x8*)(p + ks * 32) : z;
        }
      }
    }

    // ---- epilogue: softmax partials (mt-outer; per-nt accumulation order
    // identical to previous kernel => bit-identical results). tf read as
    // guarded aligned float4 from global (row0 multiple of 4, row0<100 =>
    // row0<=96, never crosses row end; base 16B-aligned since 100%4==0).
    const int lenb = sLen[c][it];
    const float* tfp = (c ? tf_user : tf_item) + (size_t)(bg4 + it) * SEQ;
    float dens[3] = {0.f, 0.f, 0.f};
    float nums[3] = {0.f, 0.f, 0.f};
    #pragma unroll
    for (int mt = 0; mt < 3; ++mt) {
      const int row0 = wm * 64 + mt * 16 + quad * 4;
      float4 tfv = {0.f, 0.f, 0.f, 0.f};
      if (row0 < SEQ) tfv = *(const float4*)(tfp + row0);
      float wv[4];
      wv[0] = (row0 + 0 < lenb) ? tfv.x : 0.f;
      wv[1] = (row0 + 1 < lenb) ? tfv.y : 0.f;
      wv[2] = (row0 + 2 < lenb) ? tfv.z : 0.f;
      wv[3] = (row0 + 3 < lenb) ? tfv.w : 0.f;
      #pragma unroll
      for (int nt = 0; nt < 3; ++nt)
        #pragma unroll
        for (int r = 0; r < 4; ++r) {
          const float v = acc[mt][nt][r];
          const float e = __expf(v);
          dens[nt] += e;
          nums[nt] = fmaf(wv[r], e * v, nums[nt]);
        }
    }
    if (wm == 0) {   // wave-uniform; static index acc[3][nt]; rows 48..63
      const int row0 = 3 * 16 + quad * 4;
      float4 tfv = *(const float4*)(tfp + row0);
      float wv[4];
      wv[0] = (row0 + 0 < lenb) ? tfv.x : 0.f;
      wv[1] = (row0 + 1 < lenb) ? tfv.y : 0.f;
      wv[2] = (row0 + 2 < lenb) ? tfv.z : 0.f;
      wv[3] = (row0 + 3 < lenb) ? tfv.w : 0.f;
      #pragma unroll
      for (int nt = 0; nt < 3; ++nt)
        #pragma unroll
        for (int r = 0; r < 4; ++r) {
          const float v = acc[3][nt][r];
          const float e = __expf(v);
          dens[nt] += e;
          nums[nt] = fmaf(wv[r], e * v, nums[nt]);
        }
    }

    #pragma unroll
    for (int nt = 0; nt < 3; ++nt) {
      float den = dens[nt], num = nums[nt];
      den += __shfl_xor(den, 16, 64);
      den += __shfl_xor(den, 32, 64);
      num += __shfl_xor(num, 16, 64);
      num += __shfl_xor(num, 32, 64);
      const int col = wn * 48 + nt * 16 + l15;
      if (quad == 0) {
        sDen[buf][wm][col] = den;
        sNum[buf][wm][col] = num;
      }
      // row 100 = wm1, mt2, quad1, r0
      if (wm == 1 && quad == 1) sDir[buf][col] = acc[2][nt][0];
    }
  }

  __syncthreads();

  // ---- combine final stage (ps=7, parity 1, it=3) ----
  if (t < BN) {
    float den = sDen[1][0][t] + sDen[1][1][t];
    float num = sNum[1][0][t] + sNum[1][1][t];
    const float dir = sDir[1][t];
    den -= 11.f + __expf(dir);
    const float val = num * __builtin_amdgcn_rcpf(den) + dir;
    const int v = v0 + t;
    if (v < VDIM) out[(size_t)(bg4 + 3) * VDIM + v] = sRes[3][t] + val;
  }
}

extern "C" void kernel_launch(void* const* d_in, const int* in_sizes, int n_in,
                              void* d_out, int out_size, void* d_ws, size_t ws_size,
                              hipStream_t stream) {
  const int*   attr_item = (const int*)d_in[0];
  const float* tf_item   = (const float*)d_in[1];
  const int*   lens_item = (const int*)d_in[2];
  const int*   item_ids  = (const int*)d_in[3];
  const int*   attr_user = (const int*)d_in[4];
  const float* tf_user   = (const float*)d_in[5];
  const int*   lens_user = (const int*)d_in[6];
  const int*   user_ids  = (const int*)d_in[7];
  const float* W_item    = (const float*)d_in[8];
  const float* W_user    = (const float*)d_in[9];
  const float* user_emb  = (const float*)d_in[10];
  const float* item_emb  = (const float*)d_in[11];
  float* out = (float*)d_out;

  unsigned short* wbf = (unsigned short*)d_ws;                  // [2][V][E] bf16 (linear)
  unsigned short* abf = wbf + (size_t)2 * VDIM * EDIM;          // [2][64] swizzled 28KB tiles

  prep_kernel<<<dim3(2500 + 128), 256, 0, stream>>>(W_item, W_user, attr_item, attr_user,
                                                    item_ids, user_ids, item_emb, user_emb,
                                                    wbf, abf);
  main_kernel<<<dim3(NVT, 16), 256, 0, stream>>>(wbf, abf, tf_item, lens_item,
                                                 tf_user, lens_user, out);
}

// Round 3
// 243.409 us; speedup vs baseline: 1.8143x; 1.8143x over previous
//
#include <hip/hip_runtime.h>

#define VDIM 20000
#define EDIM 128
#define BATCH 64
#define SEQ 100
#define BN 64
#define NVT 313   // ceil(20000/64)
#define AROWS 112
#define ATILE (AROWS * EDIM)   // 14336 shorts = 28 KB
#define GRID (NVT * 16)        // 5008 blocks
#define GPX (GRID / 8)         // 626 per XCD

typedef float f32x4 __attribute__((ext_vector_type(4)));
typedef short bf16x8 __attribute__((ext_vector_type(8)));
typedef unsigned short ushortx8 __attribute__((ext_vector_type(8)));

typedef __attribute__((address_space(1))) const unsigned int gas_u32;
typedef __attribute__((address_space(3))) unsigned int las_u32;

__device__ __forceinline__ void async16(unsigned short* lds, const unsigned short* g) {
  __builtin_amdgcn_global_load_lds((gas_u32*)g, (las_u32*)lds, 16, 0, 0);
}

__device__ __forceinline__ unsigned short f2bf(float f) {
  unsigned u = __builtin_bit_cast(unsigned, f);
  u += 0x7FFFu + ((u >> 16) & 1u);   // RTNE
  return (unsigned short)(u >> 16);
}

// ---- fused prep: W->bf16 (blocks 0..2499) + A gather PRE-SWIZZLED (2500..2627)
// A tiles: 112 rows. 0..99 = W[attr], 100 = direct emb, 101..111 = zero pads.
__global__ void prep_kernel(const float* __restrict__ Wi, const float* __restrict__ Wu,
                            const int* __restrict__ attr_item, const int* __restrict__ attr_user,
                            const int* __restrict__ item_ids, const int* __restrict__ user_ids,
                            const float* __restrict__ item_emb, const float* __restrict__ user_emb,
                            unsigned short* __restrict__ wbf, unsigned short* __restrict__ abf) {
  const int bid = blockIdx.x, t = threadIdx.x;
  if (bid < 2500) {
    const int c = bid & 1;
    const float* src = c ? Wu : Wi;
    unsigned short* dst = wbf + (size_t)c * (VDIM * EDIM);
    const int i0 = ((bid >> 1) * 256 + t) * 8;
    float4 a = *(const float4*)(src + i0);
    float4 b = *(const float4*)(src + i0 + 4);
    ushortx8 o;
    o[0] = f2bf(a.x); o[1] = f2bf(a.y); o[2] = f2bf(a.z); o[3] = f2bf(a.w);
    o[4] = f2bf(b.x); o[5] = f2bf(b.y); o[6] = f2bf(b.z); o[7] = f2bf(b.w);
    *(ushortx8*)(dst + i0) = o;
  } else {
    const int g = bid - 2500;
    const int b = g & 63, c = g >> 6;
    const int r = t >> 1, h = t & 1;
    if (r >= AROWS) return;
    const int* ids = c ? attr_user : attr_item;
    const float* W = c ? Wu : Wi;
    const float* demb = c ? user_emb : item_emb;
    const int* dids = c ? user_ids : item_ids;
    unsigned short* dst = abf + (size_t)(c * BATCH + b) * ATILE;
    const float* src = nullptr;
    if (r < SEQ)       src = W + (size_t)ids[b * SEQ + r] * EDIM;
    else if (r == SEQ) src = demb + (size_t)dids[b] * EDIM;
    if (src) {
      #pragma unroll
      for (int k = 0; k < 8; ++k) {
        const int jj = h * 8 + k;
        const int j = jj ^ (r & 15);
        float4 a  = *(const float4*)(src + j * 8);
        float4 bb = *(const float4*)(src + j * 8 + 4);
        ushortx8 o;
        o[0] = f2bf(a.x);  o[1] = f2bf(a.y);  o[2] = f2bf(a.z);  o[3] = f2bf(a.w);
        o[4] = f2bf(bb.x); o[5] = f2bf(bb.y); o[6] = f2bf(bb.z); o[7] = f2bf(bb.w);
        *(ushortx8*)(dst + (r * 16 + jj) * 8) = o;
      }
    } else {
      ushortx8 z = {0, 0, 0, 0, 0, 0, 0, 0};
      #pragma unroll
      for (int k = 0; k < 8; ++k) *(ushortx8*)(dst + (r * 16 + h * 8 + k) * 8) = z;
    }
  }
}

// ---- main: 256 thr (4 waves: wm2 x wn2), tile 112 rows x 64 cols.
// wm0: rows 0..63 (mt0..3). wm1: rows 64..111 (mt0..2). breg 32 VGPR +
// acc 32 AGPR + af 12 => ~95 live regs => fits 128 => 4 waves/SIMD under
// __launch_bounds__(256,4). LDS ~38.4 KB => 4 blocks/CU => 16 waves/CU.
// B loaded as bf16 from wbf (NO in-register f32->bf16 conversion: that plus
// wv-live-across-MFMA is what spilled R1/R2 — WRITE_SIZE is the tripwire).
// wv computed AFTER the GEMM from sTF. All register arrays statically indexed.
// 1-D grid with XCD-concentrating swizzle: blocks sharing a v-tile (B panel)
// land on one XCD's L2 (id%8 = XCD under round-robin dispatch; locality-only).
__global__ __launch_bounds__(256, 4)
void main_kernel(const unsigned short* __restrict__ wbf, const unsigned short* __restrict__ abf,
                 const float* __restrict__ tf_item, const int* __restrict__ lens_item,
                 const float* __restrict__ tf_user, const int* __restrict__ lens_user,
                 float* __restrict__ out) {
  __shared__ __align__(16) unsigned short sA[ATILE];   // 28 KB swizzled A tile
  __shared__ float sDen[2][2][BN];                     // [parity][wm][col]
  __shared__ float sNum[2][2][BN];
  __shared__ float sDir[2][BN];
  __shared__ float sTF[2][4][128];
  __shared__ int   sLen[2][4];
  __shared__ float sRes[4][BN];

  const int t = threadIdx.x;
  const int bid = blockIdx.x;
  const int p = (bid & 7) * GPX + (bid >> 3);   // per-XCD sequential order
  const int v0 = (p >> 4) * BN;                 // 313 v-tiles, ~39 per XCD
  const int bg4 = (p & 15) * 4;                 // 16 b-groups
  const int lane = t & 63, wave = t >> 6;
  const int wm = wave >> 1, wn = wave & 1;
  const int quad = lane >> 4, l15 = lane & 15;

  // ---- stage tf / lens into LDS (shift-only indexing) ----
  #pragma unroll
  for (int k = t; k < 1024; k += 256) {
    const int c = k >> 9, bi = (k >> 7) & 3, si = k & 127;
    float w = 0.f;
    if (si < SEQ) w = (c ? tf_user : tf_item)[(bg4 + bi) * SEQ + si];
    sTF[c][bi][si] = w;
  }
  if (t < 8) sLen[t >> 2][t & 3] = ((t >= 4) ? lens_user : lens_item)[bg4 + (t & 3)];

  // ---- B fragments for cluster 0 (32 VGPRs) ----
  bf16x8 breg[2][4];
  #pragma unroll
  for (int nt = 0; nt < 2; ++nt) {
    const int v = v0 + wn * 32 + nt * 16 + l15;
    const unsigned short* pb = wbf + (size_t)v * EDIM + quad * 8;
    const bool ok = (v < VDIM);
    #pragma unroll
    for (int ks = 0; ks < 4; ++ks) {
      bf16x8 z = {0, 0, 0, 0, 0, 0, 0, 0};
      breg[nt][ks] = ok ? *(const bf16x8*)(pb + ks * 32) : z;
    }
  }

  // ---- issue async A DMA for stage 0 ----
  {
    const unsigned short* gb = abf + (size_t)bg4 * ATILE;
    #pragma unroll
    for (int i = 0; i < 7; ++i)
      async16(&sA[(i * 256 + wave * 64) * 8], gb + (size_t)(i * 256 + t) * 8);
  }

  #pragma unroll 1
  for (int s = 0; s < 8; ++s) {
    const int c = s >> 2, it = s & 3, buf = s & 1;

    __syncthreads();   // #1: DMA drained (sA = tile s); prev partials visible

    // ---- combine previous stage's partials (t<64 owns col t) ----
    if (s > 0 && t < BN) {
      const int ps = s - 1, pp = ps & 1, pit = ps & 3;
      float den = sDen[pp][0][t] + sDen[pp][1][t];
      float num = sNum[pp][0][t] + sNum[pp][1][t];
      const float dir = sDir[pp][t];
      den -= 11.f + __expf(dir);                 // 11 pad rows (101..111) + dir row
      const float val = num * __builtin_amdgcn_rcpf(den) + dir;
      if (ps < 4) sRes[pit][t] = val;
      else {
        const int v = v0 + t;
        if (v < VDIM) out[(size_t)(bg4 + pit) * VDIM + v] = sRes[pit][t] + val;
      }
    }

    // ---- GEMM: 16x16x32 tiles; A from LDS (swizzled), B from regs ----
    f32x4 acc[4][2];
    #pragma unroll
    for (int mt = 0; mt < 4; ++mt)
      #pragma unroll
      for (int nt = 0; nt < 2; ++nt) { f32x4 z = {0.f, 0.f, 0.f, 0.f}; acc[mt][nt] = z; }

    const unsigned char* pA = (const unsigned char*)&sA[0];
    #pragma unroll
    for (int ks = 0; ks < 4; ++ks) {
      const int j = ks * 4 + quad;
      const int sw = ((j ^ l15) << 4);
      bf16x8 af[3];
      #pragma unroll
      for (int mt = 0; mt < 3; ++mt)
        af[mt] = *(const bf16x8*)(pA + (wm * 64 + mt * 16 + l15) * 256 + sw);
      #pragma unroll
      for (int mt = 0; mt < 3; ++mt)
        #pragma unroll
        for (int nt = 0; nt < 2; ++nt)
          acc[mt][nt] = __builtin_amdgcn_mfma_f32_16x16x32_bf16(af[mt], breg[nt][ks], acc[mt][nt], 0, 0, 0);
      if (wm == 0) {   // wave-uniform; rows 48..63
        const bf16x8 a3 = *(const bf16x8*)(pA + (3 * 16 + l15) * 256 + sw);
        #pragma unroll
        for (int nt = 0; nt < 2; ++nt)
          acc[3][nt] = __builtin_amdgcn_mfma_f32_16x16x32_bf16(a3, breg[nt][ks], acc[3][nt], 0, 0, 0);
      }
    }

    __syncthreads();   // #2: all waves done reading sA (+ combine done)

    // ---- issue next stage's A DMA (covered by epilogue below) ----
    if (s < 7) {
      const int ns = s + 1;
      const unsigned short* gb = abf + (size_t)((ns >> 2) * BATCH + bg4 + (ns & 3)) * ATILE;
      #pragma unroll
      for (int i = 0; i < 7; ++i)
        async16(&sA[(i * 256 + wave * 64) * 8], gb + (size_t)(i * 256 + t) * 8);
    }
    // reload B for cluster 1 once (plain bf16 loads, no conversion)
    if (s == 3) {
      const unsigned short* wb1 = wbf + (size_t)VDIM * EDIM;
      #pragma unroll
      for (int nt = 0; nt < 2; ++nt) {
        const int v = v0 + wn * 32 + nt * 16 + l15;
        const unsigned short* pb = wb1 + (size_t)v * EDIM + quad * 8;
        const bool ok = (v < VDIM);
        #pragma unroll
        for (int ks = 0; ks < 4; ++ks) {
          bf16x8 z = {0, 0, 0, 0, 0, 0, 0, 0};
          breg[nt][ks] = ok ? *(const bf16x8*)(pb + ks * 32) : z;
        }
      }
    }

    // ---- epilogue: wv from sTF (AFTER MFMA: not live across it), then
    // softmax partials. Accumulation order per nt identical to R0 =>
    // bit-identical results.
    const int lenb = sLen[c][it];
    float wv[4][4];
    #pragma unroll
    for (int mt = 0; mt < 4; ++mt)
      #pragma unroll
      for (int r = 0; r < 4; ++r) {
        const int row = wm * 64 + mt * 16 + quad * 4 + r;
        wv[mt][r] = (row < lenb) ? sTF[c][it][row & 127] : 0.f;
      }

    #pragma unroll
    for (int nt = 0; nt < 2; ++nt) {
      float den = 0.f, num = 0.f;
      #pragma unroll
      for (int mt = 0; mt < 3; ++mt)
        #pragma unroll
        for (int r = 0; r < 4; ++r) {
          const float v = acc[mt][nt][r];
          const float e = __expf(v);
          den += e;
          num = fmaf(wv[mt][r], e * v, num);
        }
      if (wm == 0) {   // wave-uniform; static index acc[3][nt]
        #pragma unroll
        for (int r = 0; r < 4; ++r) {
          const float v = acc[3][nt][r];
          const float e = __expf(v);
          den += e;
          num = fmaf(wv[3][r], e * v, num);
        }
      }
      den += __shfl_xor(den, 16, 64);
      den += __shfl_xor(den, 32, 64);
      num += __shfl_xor(num, 16, 64);
      num += __shfl_xor(num, 32, 64);
      const int col = wn * 32 + nt * 16 + l15;
      if (quad == 0) {
        sDen[buf][wm][col] = den;
        sNum[buf][wm][col] = num;
      }
      // row 100 = wm1, mt2, quad1, r0
      if (wm == 1 && quad == 1) sDir[buf][col] = acc[2][nt][0];
    }
  }

  __syncthreads();

  // ---- combine final stage (ps=7, parity 1, it=3) ----
  if (t < BN) {
    float den = sDen[1][0][t] + sDen[1][1][t];
    float num = sNum[1][0][t] + sNum[1][1][t];
    const float dir = sDir[1][t];
    den -= 11.f + __expf(dir);
    const float val = num * __builtin_amdgcn_rcpf(den) + dir;
    const int v = v0 + t;
    if (v < VDIM) out[(size_t)(bg4 + 3) * VDIM + v] = sRes[3][t] + val;
  }
}

extern "C" void kernel_launch(void* const* d_in, const int* in_sizes, int n_in,
                              void* d_out, int out_size, void* d_ws, size_t ws_size,
                              hipStream_t stream) {
  const int*   attr_item = (const int*)d_in[0];
  const float* tf_item   = (const float*)d_in[1];
  const int*   lens_item = (const int*)d_in[2];
  const int*   item_ids  = (const int*)d_in[3];
  const int*   attr_user = (const int*)d_in[4];
  const float* tf_user   = (const float*)d_in[5];
  const int*   lens_user = (const int*)d_in[6];
  const int*   user_ids  = (const int*)d_in[7];
  const float* W_item    = (const float*)d_in[8];
  const float* W_user    = (const float*)d_in[9];
  const float* user_emb  = (const float*)d_in[10];
  const float* item_emb  = (const float*)d_in[11];
  float* out = (float*)d_out;

  unsigned short* wbf = (unsigned short*)d_ws;                  // [2][V][E] bf16 (linear)
  unsigned short* abf = wbf + (size_t)2 * VDIM * EDIM;          // [2][64] swizzled 28KB tiles

  prep_kernel<<<dim3(2500 + 128), 256, 0, stream>>>(W_item, W_user, attr_item, attr_user,
                                                    item_ids, user_ids, item_emb, user_emb,
                                                    wbf, abf);
  main_kernel<<<dim3(GRID), 256, 0, stream>>>(wbf, abf, tf_item, lens_item,
                                              tf_user, lens_user, out);
}

// Round 4
// 229.012 us; speedup vs baseline: 1.9283x; 1.0629x over previous
//
#include <hip/hip_runtime.h>

#define VDIM 20000
#define EDIM 128
#define BATCH 64
#define SEQ 100
#define BN 96
#define NVT 209   // ceil(20000/96)
#define AROWS 112
#define ATILE (AROWS * EDIM)   // 14336 shorts = 28 KB
#define GRID (NVT * 16)        // 3344 blocks
#define GPX (GRID / 8)         // 418 per XCD (exact)

typedef float f32x4 __attribute__((ext_vector_type(4)));
typedef float f32x2 __attribute__((ext_vector_type(2)));
typedef short bf16x8 __attribute__((ext_vector_type(8)));
typedef unsigned short ushortx8 __attribute__((ext_vector_type(8)));

typedef __attribute__((address_space(1))) const unsigned int gas_u32;
typedef __attribute__((address_space(3))) unsigned int las_u32;

__device__ __forceinline__ void async16(unsigned short* lds, const unsigned short* g) {
  __builtin_amdgcn_global_load_lds((gas_u32*)g, (las_u32*)lds, 16, 0, 0);
}

__device__ __forceinline__ unsigned short f2bf(float f) {
  unsigned u = __builtin_bit_cast(unsigned, f);
  u += 0x7FFFu + ((u >> 16) & 1u);   // RTNE
  return (unsigned short)(u >> 16);
}

// full-rate packed f32 (CDNA VOP3P); per-lane semantics identical to scalar ops
__device__ __forceinline__ f32x2 pk_mul(f32x2 a, f32x2 b) {
  f32x2 d; asm("v_pk_mul_f32 %0, %1, %2" : "=v"(d) : "v"(a), "v"(b)); return d;
}
__device__ __forceinline__ f32x2 pk_add(f32x2 a, f32x2 b) {
  f32x2 d; asm("v_pk_add_f32 %0, %1, %2" : "=v"(d) : "v"(a), "v"(b)); return d;
}
__device__ __forceinline__ f32x2 pk_fma(f32x2 a, f32x2 b, f32x2 c) {
  f32x2 d; asm("v_pk_fma_f32 %0, %1, %2, %3" : "=v"(d) : "v"(a), "v"(b), "v"(c)); return d;
}
__device__ __forceinline__ float fexp2(float x) {   // v_exp_f32: D = 2^S0
  float d; asm("v_exp_f32 %0, %1" : "=v"(d) : "v"(x)); return d;
}
#define L2E_BITS 0x3FB8AA3Bu   // RN(log2 e) — same constant __expf uses

// ---- fused prep: W->bf16 (blocks 0..2499) + A gather PRE-SWIZZLED (2500..2627)
// A tiles: 112 rows. 0..99 = W[attr], 100 = direct emb, 101..111 = zero pads.
__global__ void prep_kernel(const float* __restrict__ Wi, const float* __restrict__ Wu,
                            const int* __restrict__ attr_item, const int* __restrict__ attr_user,
                            const int* __restrict__ item_ids, const int* __restrict__ user_ids,
                            const float* __restrict__ item_emb, const float* __restrict__ user_emb,
                            unsigned short* __restrict__ wbf, unsigned short* __restrict__ abf) {
  const int bid = blockIdx.x, t = threadIdx.x;
  if (bid < 2500) {
    const int c = bid & 1;
    const float* src = c ? Wu : Wi;
    unsigned short* dst = wbf + (size_t)c * (VDIM * EDIM);
    const int i0 = ((bid >> 1) * 256 + t) * 8;
    float4 a = *(const float4*)(src + i0);
    float4 b = *(const float4*)(src + i0 + 4);
    ushortx8 o;
    o[0] = f2bf(a.x); o[1] = f2bf(a.y); o[2] = f2bf(a.z); o[3] = f2bf(a.w);
    o[4] = f2bf(b.x); o[5] = f2bf(b.y); o[6] = f2bf(b.z); o[7] = f2bf(b.w);
    *(ushortx8*)(dst + i0) = o;
  } else {
    const int g = bid - 2500;
    const int b = g & 63, c = g >> 6;
    const int r = t >> 1, h = t & 1;
    if (r >= AROWS) return;
    const int* ids = c ? attr_user : attr_item;
    const float* W = c ? Wu : Wi;
    const float* demb = c ? user_emb : item_emb;
    const int* dids = c ? user_ids : item_ids;
    unsigned short* dst = abf + (size_t)(c * BATCH + b) * ATILE;
    const float* src = nullptr;
    if (r < SEQ)       src = W + (size_t)ids[b * SEQ + r] * EDIM;
    else if (r == SEQ) src = demb + (size_t)dids[b] * EDIM;
    if (src) {
      #pragma unroll
      for (int k = 0; k < 8; ++k) {
        const int jj = h * 8 + k;
        const int j = jj ^ (r & 15);
        float4 a  = *(const float4*)(src + j * 8);
        float4 bb = *(const float4*)(src + j * 8 + 4);
        ushortx8 o;
        o[0] = f2bf(a.x);  o[1] = f2bf(a.y);  o[2] = f2bf(a.z);  o[3] = f2bf(a.w);
        o[4] = f2bf(bb.x); o[5] = f2bf(bb.y); o[6] = f2bf(bb.z); o[7] = f2bf(bb.w);
        *(ushortx8*)(dst + (r * 16 + jj) * 8) = o;
      }
    } else {
      ushortx8 z = {0, 0, 0, 0, 0, 0, 0, 0};
      #pragma unroll
      for (int k = 0; k < 8; ++k) *(ushortx8*)(dst + (r * 16 + h * 8 + k) * 8) = z;
    }
  }
}

// ---- main: 256 thr (4 waves: wm2 x wn2), tile 112 rows x 96 cols.
// wm0: rows 0..63 (mt0..3). wm1: rows 64..111 (mt0..2). breg 48 + acc 48 =>
// ~160 regs => (256,3), 3 blocks/CU — R0's proven-no-spill configuration.
// Epilogue VALU halved: pre-masked sTF (no per-element guard) + packed-f32
// chain (pk_mul scale / v_exp / pk_add den / pk_mul ev / pk_fma num).
// e is bit-identical to __expf (same 0x3FB8AA3B constant + v_exp); only the
// den/num summation is pairwise-reassociated (~1e-7 rel, << bf16 noise).
// 1-D grid, XCD-concentrating swizzle (proven FETCH -50%). All register
// arrays statically indexed.
__global__ __launch_bounds__(256, 3)
void main_kernel(const unsigned short* __restrict__ wbf, const unsigned short* __restrict__ abf,
                 const float* __restrict__ tf_item, const int* __restrict__ lens_item,
                 const float* __restrict__ tf_user, const int* __restrict__ lens_user,
                 float* __restrict__ out) {
  __shared__ __align__(16) unsigned short sA[ATILE];   // 28 KB swizzled A tile
  __shared__ float sDen[2][2][BN];                     // [parity][wm][col]
  __shared__ float sNum[2][2][BN];
  __shared__ float sDir[2][BN];
  __shared__ __align__(16) float sTF[2][4][128];       // pre-masked: >=len and >=SEQ are 0
  __shared__ float sRes[4][BN];

  const int t = threadIdx.x;
  const int bid = blockIdx.x;
  const int p = (bid & 7) * GPX + (bid >> 3);   // per-XCD sequential order
  const int v0 = (p >> 4) * BN;                 // 209 v-tiles
  const int bg4 = (p & 15) * 4;                 // 16 b-groups
  const int lane = t & 63, wave = t >> 6;
  const int wm = wave >> 1, wn = wave & 1;
  const int quad = lane >> 4, l15 = lane & 15;
  const float L2E = __builtin_bit_cast(float, L2E_BITS);
  const f32x2 L2E2 = {L2E, L2E};

  // ---- stage tf into LDS, PRE-MASKED by lens (kills per-element guards) ----
  #pragma unroll
  for (int k = t; k < 1024; k += 256) {
    const int c = k >> 9, bi = (k >> 7) & 3, si = k & 127;
    const int lb = (c ? lens_user : lens_item)[bg4 + bi];
    float w = 0.f;
    if (si < lb) w = (c ? tf_user : tf_item)[(bg4 + bi) * SEQ + si];   // lb<=SEQ
    sTF[c][bi][si] = w;
  }

  // ---- B fragments for cluster 0 (48 VGPRs) ----
  bf16x8 breg[3][4];
  #pragma unroll
  for (int nt = 0; nt < 3; ++nt) {
    const int v = v0 + wn * 48 + nt * 16 + l15;
    const unsigned short* pb = wbf + (size_t)v * EDIM + quad * 8;
    const bool ok = (v < VDIM);
    #pragma unroll
    for (int ks = 0; ks < 4; ++ks) {
      bf16x8 z = {0, 0, 0, 0, 0, 0, 0, 0};
      breg[nt][ks] = ok ? *(const bf16x8*)(pb + ks * 32) : z;
    }
  }

  // ---- issue async A DMA for stage 0 ----
  {
    const unsigned short* gb = abf + (size_t)bg4 * ATILE;
    #pragma unroll
    for (int i = 0; i < 7; ++i)
      async16(&sA[(i * 256 + wave * 64) * 8], gb + (size_t)(i * 256 + t) * 8);
  }

  #pragma unroll 1
  for (int s = 0; s < 8; ++s) {
    const int cc = s >> 2, it = s & 3, buf = s & 1;

    __syncthreads();   // #1: DMA drained (sA = tile s); prev partials visible

    // ---- combine previous stage's partials (t<96 owns col t) ----
    if (s > 0 && t < BN) {
      const int ps = s - 1, pp = ps & 1, pit = ps & 3;
      float den = sDen[pp][0][t] + sDen[pp][1][t];
      float num = sNum[pp][0][t] + sNum[pp][1][t];
      const float dir = sDir[pp][t];
      const float dirE = fexp2(dir * L2E);       // same path as epilogue's den term
      den -= 11.f + dirE;                        // 11 pad rows (101..111) + dir row
      const float val = num * __builtin_amdgcn_rcpf(den) + dir;
      if (ps < 4) sRes[pit][t] = val;
      else {
        const int v = v0 + t;
        if (v < VDIM) out[(size_t)(bg4 + pit) * VDIM + v] = sRes[pit][t] + val;
      }
    }

    // ---- GEMM: 16x16x32 tiles; A from LDS (swizzled), B from regs ----
    f32x4 acc[4][3];
    #pragma unroll
    for (int mt = 0; mt < 4; ++mt)
      #pragma unroll
      for (int nt = 0; nt < 3; ++nt) { f32x4 z = {0.f, 0.f, 0.f, 0.f}; acc[mt][nt] = z; }

    const unsigned char* pA = (const unsigned char*)&sA[0];
    #pragma unroll
    for (int ks = 0; ks < 4; ++ks) {
      const int j = ks * 4 + quad;
      const int sw = ((j ^ l15) << 4);
      bf16x8 af[3];
      #pragma unroll
      for (int mt = 0; mt < 3; ++mt)
        af[mt] = *(const bf16x8*)(pA + (wm * 64 + mt * 16 + l15) * 256 + sw);
      #pragma unroll
      for (int mt = 0; mt < 3; ++mt)
        #pragma unroll
        for (int nt = 0; nt < 3; ++nt)
          acc[mt][nt] = __builtin_amdgcn_mfma_f32_16x16x32_bf16(af[mt], breg[nt][ks], acc[mt][nt], 0, 0, 0);
      if (wm == 0) {   // wave-uniform; rows 48..63
        const bf16x8 a3 = *(const bf16x8*)(pA + (3 * 16 + l15) * 256 + sw);
        #pragma unroll
        for (int nt = 0; nt < 3; ++nt)
          acc[3][nt] = __builtin_amdgcn_mfma_f32_16x16x32_bf16(a3, breg[nt][ks], acc[3][nt], 0, 0, 0);
      }
    }

    __syncthreads();   // #2: all waves done reading sA (+ combine done)

    // ---- issue next stage's A DMA (covered by epilogue below) ----
    if (s < 7) {
      const int ns = s + 1;
      const unsigned short* gb = abf + (size_t)((ns >> 2) * BATCH + bg4 + (ns & 3)) * ATILE;
      #pragma unroll
      for (int i = 0; i < 7; ++i)
        async16(&sA[(i * 256 + wave * 64) * 8], gb + (size_t)(i * 256 + t) * 8);
    }
    // reload B for cluster 1 once
    if (s == 3) {
      const unsigned short* wb1 = wbf + (size_t)VDIM * EDIM;
      #pragma unroll
      for (int nt = 0; nt < 3; ++nt) {
        const int v = v0 + wn * 48 + nt * 16 + l15;
        const unsigned short* pb = wb1 + (size_t)v * EDIM + quad * 8;
        const bool ok = (v < VDIM);
        #pragma unroll
        for (int ks = 0; ks < 4; ++ks) {
          bf16x8 z = {0, 0, 0, 0, 0, 0, 0, 0};
          breg[nt][ks] = ok ? *(const bf16x8*)(pb + ks * 32) : z;
        }
      }
    }

    // ---- epilogue: packed-f32 softmax partials ----
    // wv pairs from pre-masked sTF (16B-aligned vector reads, zero guards).
    f32x2 wlo[4], whi[4];
    #pragma unroll
    for (int mt = 0; mt < 4; ++mt) {
      const int row0 = wm * 64 + mt * 16 + quad * 4;   // <=124 < 128, pad region is 0
      const f32x4 w4 = *(const f32x4*)&sTF[cc][it][row0];
      f32x2 a = {w4[0], w4[1]}; f32x2 b = {w4[2], w4[3]};
      wlo[mt] = a; whi[mt] = b;
    }

    #pragma unroll
    for (int nt = 0; nt < 3; ++nt) {
      f32x2 den2 = {0.f, 0.f}, num2 = {0.f, 0.f};

      #define EPAIRS(MT)                                                  \
      {                                                                   \
        const f32x4 a4 = acc[MT][nt];                                     \
        const f32x2 vlo = {a4[0], a4[1]};                                 \
        const f32x2 vhi = {a4[2], a4[3]};                                 \
        const f32x2 mlo = pk_mul(vlo, L2E2);                              \
        const f32x2 mhi = pk_mul(vhi, L2E2);                              \
        f32x2 elo, ehi;                                                   \
        elo[0] = fexp2(mlo[0]); elo[1] = fexp2(mlo[1]);                   \
        ehi[0] = fexp2(mhi[0]); ehi[1] = fexp2(mhi[1]);                   \
        den2 = pk_add(den2, elo);                                         \
        den2 = pk_add(den2, ehi);                                         \
        num2 = pk_fma(wlo[MT], pk_mul(elo, vlo), num2);                   \
        num2 = pk_fma(whi[MT], pk_mul(ehi, vhi), num2);                   \
      }
      EPAIRS(0)
      EPAIRS(1)
      EPAIRS(2)
      if (wm == 0) EPAIRS(3)   // wave-uniform; static acc[3][nt]
      #undef EPAIRS

      float den = den2[0] + den2[1];
      float num = num2[0] + num2[1];
      den += __shfl_xor(den, 16, 64);
      den += __shfl_xor(den, 32, 64);
      num += __shfl_xor(num, 16, 64);
      num += __shfl_xor(num, 32, 64);
      const int col = wn * 48 + nt * 16 + l15;
      if (quad == 0) {
        sDen[buf][wm][col] = den;
        sNum[buf][wm][col] = num;
      }
      // row 100 = wm1, mt2, quad1, r0
      if (wm == 1 && quad == 1) sDir[buf][col] = acc[2][nt][0];
    }
  }

  __syncthreads();

  // ---- combine final stage (ps=7, parity 1, it=3) ----
  if (t < BN) {
    float den = sDen[1][0][t] + sDen[1][1][t];
    float num = sNum[1][0][t] + sNum[1][1][t];
    const float dir = sDir[1][t];
    const float dirE = fexp2(dir * L2E);
    den -= 11.f + dirE;
    const float val = num * __builtin_amdgcn_rcpf(den) + dir;
    const int v = v0 + t;
    if (v < VDIM) out[(size_t)(bg4 + 3) * VDIM + v] = sRes[3][t] + val;
  }
}

extern "C" void kernel_launch(void* const* d_in, const int* in_sizes, int n_in,
                              void* d_out, int out_size, void* d_ws, size_t ws_size,
                              hipStream_t stream) {
  const int*   attr_item = (const int*)d_in[0];
  const float* tf_item   = (const float*)d_in[1];
  const int*   lens_item = (const int*)d_in[2];
  const int*   item_ids  = (const int*)d_in[3];
  const int*   attr_user = (const int*)d_in[4];
  const float* tf_user   = (const float*)d_in[5];
  const int*   lens_user = (const int*)d_in[6];
  const int*   user_ids  = (const int*)d_in[7];
  const float* W_item    = (const float*)d_in[8];
  const float* W_user    = (const float*)d_in[9];
  const float* user_emb  = (const float*)d_in[10];
  const float* item_emb  = (const float*)d_in[11];
  float* out = (float*)d_out;

  unsigned short* wbf = (unsigned short*)d_ws;                  // [2][V][E] bf16 (linear)
  unsigned short* abf = wbf + (size_t)2 * VDIM * EDIM;          // [2][64] swizzled 28KB tiles

  prep_kernel<<<dim3(2500 + 128), 256, 0, stream>>>(W_item, W_user, attr_item, attr_user,
                                                    item_ids, user_ids, item_emb, user_emb,
                                                    wbf, abf);
  main_kernel<<<dim3(GRID), 256, 0, stream>>>(wbf, abf, tf_item, lens_item,
                                              tf_user, lens_user, out);
}

// Round 5
// 225.165 us; speedup vs baseline: 1.9613x; 1.0171x over previous
//
#include <hip/hip_runtime.h>

#define VDIM 20000
#define EDIM 128
#define BATCH 64
#define SEQ 100
#define BN 128
#define NVT 157   // ceil(20000/128)
#define AROWS 112
#define ATILE (AROWS * EDIM)   // 14336 shorts = 28 KB
#define GRID (NVT * 16)        // 2512 blocks
#define GPX (GRID / 8)         // 314 per XCD (exact)

typedef float f32x4 __attribute__((ext_vector_type(4)));
typedef float f32x2 __attribute__((ext_vector_type(2)));
typedef short bf16x8 __attribute__((ext_vector_type(8)));
typedef unsigned short ushortx8 __attribute__((ext_vector_type(8)));

typedef __attribute__((address_space(1))) const unsigned int gas_u32;
typedef __attribute__((address_space(3))) unsigned int las_u32;

__device__ __forceinline__ void async16(unsigned short* lds, const unsigned short* g) {
  __builtin_amdgcn_global_load_lds((gas_u32*)g, (las_u32*)lds, 16, 0, 0);
}

__device__ __forceinline__ unsigned short f2bf(float f) {
  unsigned u = __builtin_bit_cast(unsigned, f);
  u += 0x7FFFu + ((u >> 16) & 1u);   // RTNE
  return (unsigned short)(u >> 16);
}

// full-rate packed f32 (CDNA VOP3P); per-lane semantics identical to scalar ops
__device__ __forceinline__ f32x2 pk_mul(f32x2 a, f32x2 b) {
  f32x2 d; asm("v_pk_mul_f32 %0, %1, %2" : "=v"(d) : "v"(a), "v"(b)); return d;
}
__device__ __forceinline__ f32x2 pk_add(f32x2 a, f32x2 b) {
  f32x2 d; asm("v_pk_add_f32 %0, %1, %2" : "=v"(d) : "v"(a), "v"(b)); return d;
}
__device__ __forceinline__ f32x2 pk_fma(f32x2 a, f32x2 b, f32x2 c) {
  f32x2 d; asm("v_pk_fma_f32 %0, %1, %2, %3" : "=v"(d) : "v"(a), "v"(b), "v"(c)); return d;
}
__device__ __forceinline__ float fexp2(float x) {   // v_exp_f32: D = 2^S0
  float d; asm("v_exp_f32 %0, %1" : "=v"(d) : "v"(x)); return d;
}
#define L2E_BITS 0x3FB8AA3Bu   // RN(log2 e) — same constant __expf uses

// ---- fused prep: W->bf16 (blocks 0..2499) + A gather PRE-SWIZZLED (2500..2627)
// A tiles: 112 rows. 0..99 = W[attr], 100 = direct emb, 101..111 = zero pads.
__global__ void prep_kernel(const float* __restrict__ Wi, const float* __restrict__ Wu,
                            const int* __restrict__ attr_item, const int* __restrict__ attr_user,
                            const int* __restrict__ item_ids, const int* __restrict__ user_ids,
                            const float* __restrict__ item_emb, const float* __restrict__ user_emb,
                            unsigned short* __restrict__ wbf, unsigned short* __restrict__ abf) {
  const int bid = blockIdx.x, t = threadIdx.x;
  if (bid < 2500) {
    const int c = bid & 1;
    const float* src = c ? Wu : Wi;
    unsigned short* dst = wbf + (size_t)c * (VDIM * EDIM);
    const int i0 = ((bid >> 1) * 256 + t) * 8;
    float4 a = *(const float4*)(src + i0);
    float4 b = *(const float4*)(src + i0 + 4);
    ushortx8 o;
    o[0] = f2bf(a.x); o[1] = f2bf(a.y); o[2] = f2bf(a.z); o[3] = f2bf(a.w);
    o[4] = f2bf(b.x); o[5] = f2bf(b.y); o[6] = f2bf(b.z); o[7] = f2bf(b.w);
    *(ushortx8*)(dst + i0) = o;
  } else {
    const int g = bid - 2500;
    const int b = g & 63, c = g >> 6;
    const int r = t >> 1, h = t & 1;
    if (r >= AROWS) return;
    const int* ids = c ? attr_user : attr_item;
    const float* W = c ? Wu : Wi;
    const float* demb = c ? user_emb : item_emb;
    const int* dids = c ? user_ids : item_ids;
    unsigned short* dst = abf + (size_t)(c * BATCH + b) * ATILE;
    const float* src = nullptr;
    if (r < SEQ)       src = W + (size_t)ids[b * SEQ + r] * EDIM;
    else if (r == SEQ) src = demb + (size_t)dids[b] * EDIM;
    if (src) {
      #pragma unroll
      for (int k = 0; k < 8; ++k) {
        const int jj = h * 8 + k;
        const int j = jj ^ (r & 15);
        float4 a  = *(const float4*)(src + j * 8);
        float4 bb = *(const float4*)(src + j * 8 + 4);
        ushortx8 o;
        o[0] = f2bf(a.x);  o[1] = f2bf(a.y);  o[2] = f2bf(a.z);  o[3] = f2bf(a.w);
        o[4] = f2bf(bb.x); o[5] = f2bf(bb.y); o[6] = f2bf(bb.z); o[7] = f2bf(bb.w);
        *(ushortx8*)(dst + (r * 16 + jj) * 8) = o;
      }
    } else {
      ushortx8 z = {0, 0, 0, 0, 0, 0, 0, 0};
      #pragma unroll
      for (int k = 0; k < 8; ++k) *(ushortx8*)(dst + (r * 16 + h * 8 + k) * 8) = z;
    }
  }
}

// ---- main: 512 thr (8 waves: wm2 x wn4), tile 112 rows x 128 cols.
// Per wave: 4mt x 2nt => acc[4][2]=32 AGPR + breg[2][4]=32 VGPR => ~105 live
// regs => fits __launch_bounds__(512,4)'s 128 cap => 4 waves/SIMD =>
// 2 blocks/CU x 8 waves = 16 waves/CU (was 12). LDS 44 KB (3 blocks/CU —
// not binding). Fewer, fatter blocks (2512 vs 3344) amortize per-block fixed
// VALU (the R3 failure mode). Numerics identical to R4 (packed epilogue,
// same per-nt accumulation order). WRITE_SIZE is the spill tripwire.
// All register arrays statically indexed. XCD-concentrating swizzle.
__global__ __launch_bounds__(512, 4)
void main_kernel(const unsigned short* __restrict__ wbf, const unsigned short* __restrict__ abf,
                 const float* __restrict__ tf_item, const int* __restrict__ lens_item,
                 const float* __restrict__ tf_user, const int* __restrict__ lens_user,
                 float* __restrict__ out) {
  __shared__ __align__(16) unsigned short sA[ATILE];   // 28 KB swizzled A tile
  __shared__ float sDen[2][2][BN];                     // [parity][wm][col] 4 KB
  __shared__ float sNum[2][2][BN];                     // 4 KB
  __shared__ float sDir[2][BN];                        // 1 KB
  __shared__ __align__(16) float sTF[2][4][128];       // pre-masked; 4 KB
  __shared__ float sRes[4][BN];                        // 2 KB

  const int t = threadIdx.x;
  const int bid = blockIdx.x;
  const int p = (bid & 7) * GPX + (bid >> 3);   // per-XCD sequential order
  const int v0 = (p >> 4) * BN;                 // 157 v-tiles
  const int bg4 = (p & 15) * 4;                 // 16 b-groups
  const int lane = t & 63, wave = t >> 6;
  const int wm = wave >> 2, wn = wave & 3;
  const int quad = lane >> 4, l15 = lane & 15;
  const float L2E = __builtin_bit_cast(float, L2E_BITS);
  const f32x2 L2E2 = {L2E, L2E};

  // ---- stage tf into LDS, PRE-MASKED by lens (kills per-element guards) ----
  #pragma unroll
  for (int k = t; k < 1024; k += 512) {
    const int c = k >> 9, bi = (k >> 7) & 3, si = k & 127;
    const int lb = (c ? lens_user : lens_item)[bg4 + bi];
    float w = 0.f;
    if (si < lb) w = (c ? tf_user : tf_item)[(bg4 + bi) * SEQ + si];   // lb<=SEQ
    sTF[c][bi][si] = w;
  }

  // ---- B fragments for cluster 0 (32 VGPRs) ----
  bf16x8 breg[2][4];
  #pragma unroll
  for (int nt = 0; nt < 2; ++nt) {
    const int v = v0 + wn * 32 + nt * 16 + l15;
    const unsigned short* pb = wbf + (size_t)v * EDIM + quad * 8;
    const bool ok = (v < VDIM);
    #pragma unroll
    for (int ks = 0; ks < 4; ++ks) {
      bf16x8 z = {0, 0, 0, 0, 0, 0, 0, 0};
      breg[nt][ks] = ok ? *(const bf16x8*)(pb + ks * 32) : z;
    }
  }

  // ---- issue async A DMA for stage 0 (512-thread mapping: 3.5 iters) ----
  {
    const unsigned short* gb = abf + (size_t)bg4 * ATILE;
    #pragma unroll
    for (int i = 0; i < 3; ++i)
      async16(&sA[(i * 512 + wave * 64) * 8], gb + (size_t)(i * 512 + t) * 8);
    if (t < 256)   // waves 0..3 cover shorts 12288..14335
      async16(&sA[(1536 + wave * 64) * 8], gb + (size_t)(1536 + t) * 8);
  }

  #pragma unroll 1
  for (int s = 0; s < 8; ++s) {
    const int cc = s >> 2, it = s & 3, buf = s & 1;

    __syncthreads();   // #1: DMA drained (sA = tile s); prev partials visible

    // ---- combine previous stage's partials (t<128 owns col t) ----
    if (s > 0 && t < BN) {
      const int ps = s - 1, pp = ps & 1, pit = ps & 3;
      float den = sDen[pp][0][t] + sDen[pp][1][t];
      float num = sNum[pp][0][t] + sNum[pp][1][t];
      const float dir = sDir[pp][t];
      const float dirE = fexp2(dir * L2E);       // same path as epilogue's den term
      den -= 11.f + dirE;                        // 11 pad rows (101..111) + dir row
      const float val = num * __builtin_amdgcn_rcpf(den) + dir;
      if (ps < 4) sRes[pit][t] = val;
      else {
        const int v = v0 + t;
        if (v < VDIM) out[(size_t)(bg4 + pit) * VDIM + v] = sRes[pit][t] + val;
      }
    }

    // ---- GEMM: 16x16x32 tiles; A from LDS (swizzled), B from regs ----
    f32x4 acc[4][2];
    #pragma unroll
    for (int mt = 0; mt < 4; ++mt)
      #pragma unroll
      for (int nt = 0; nt < 2; ++nt) { f32x4 z = {0.f, 0.f, 0.f, 0.f}; acc[mt][nt] = z; }

    const unsigned char* pA = (const unsigned char*)&sA[0];
    #pragma unroll
    for (int ks = 0; ks < 4; ++ks) {
      const int j = ks * 4 + quad;
      const int sw = ((j ^ l15) << 4);
      bf16x8 af[3];
      #pragma unroll
      for (int mt = 0; mt < 3; ++mt)
        af[mt] = *(const bf16x8*)(pA + (wm * 64 + mt * 16 + l15) * 256 + sw);
      #pragma unroll
      for (int mt = 0; mt < 3; ++mt)
        #pragma unroll
        for (int nt = 0; nt < 2; ++nt)
          acc[mt][nt] = __builtin_amdgcn_mfma_f32_16x16x32_bf16(af[mt], breg[nt][ks], acc[mt][nt], 0, 0, 0);
      if (wm == 0) {   // wave-uniform; rows 48..63
        const bf16x8 a3 = *(const bf16x8*)(pA + (3 * 16 + l15) * 256 + sw);
        #pragma unroll
        for (int nt = 0; nt < 2; ++nt)
          acc[3][nt] = __builtin_amdgcn_mfma_f32_16x16x32_bf16(a3, breg[nt][ks], acc[3][nt], 0, 0, 0);
      }
    }

    __syncthreads();   // #2: all waves done reading sA (+ combine done)

    // ---- issue next stage's A DMA (covered by epilogue below) ----
    if (s < 7) {
      const int ns = s + 1;
      const unsigned short* gb = abf + (size_t)((ns >> 2) * BATCH + bg4 + (ns & 3)) * ATILE;
      #pragma unroll
      for (int i = 0; i < 3; ++i)
        async16(&sA[(i * 512 + wave * 64) * 8], gb + (size_t)(i * 512 + t) * 8);
      if (t < 256)
        async16(&sA[(1536 + wave * 64) * 8], gb + (size_t)(1536 + t) * 8);
    }
    // reload B for cluster 1 once
    if (s == 3) {
      const unsigned short* wb1 = wbf + (size_t)VDIM * EDIM;
      #pragma unroll
      for (int nt = 0; nt < 2; ++nt) {
        const int v = v0 + wn * 32 + nt * 16 + l15;
        const unsigned short* pb = wb1 + (size_t)v * EDIM + quad * 8;
        const bool ok = (v < VDIM);
        #pragma unroll
        for (int ks = 0; ks < 4; ++ks) {
          bf16x8 z = {0, 0, 0, 0, 0, 0, 0, 0};
          breg[nt][ks] = ok ? *(const bf16x8*)(pb + ks * 32) : z;
        }
      }
    }

    // ---- epilogue: packed-f32 softmax partials (identical math to R4) ----
    f32x2 wlo[4], whi[4];
    #pragma unroll
    for (int mt = 0; mt < 4; ++mt) {
      const int row0 = wm * 64 + mt * 16 + quad * 4;   // <=124 < 128, pad region is 0
      const f32x4 w4 = *(const f32x4*)&sTF[cc][it][row0];
      f32x2 a = {w4[0], w4[1]}; f32x2 b = {w4[2], w4[3]};
      wlo[mt] = a; whi[mt] = b;
    }

    #pragma unroll
    for (int nt = 0; nt < 2; ++nt) {
      f32x2 den2 = {0.f, 0.f}, num2 = {0.f, 0.f};

      #define EPAIRS(MT)                                                  \
      {                                                                   \
        const f32x4 a4 = acc[MT][nt];                                     \
        const f32x2 vlo = {a4[0], a4[1]};                                 \
        const f32x2 vhi = {a4[2], a4[3]};                                 \
        const f32x2 mlo = pk_mul(vlo, L2E2);                              \
        const f32x2 mhi = pk_mul(vhi, L2E2);                              \
        f32x2 elo, ehi;                                                   \
        elo[0] = fexp2(mlo[0]); elo[1] = fexp2(mlo[1]);                   \
        ehi[0] = fexp2(mhi[0]); ehi[1] = fexp2(mhi[1]);                   \
        den2 = pk_add(den2, elo);                                         \
        den2 = pk_add(den2, ehi);                                         \
        num2 = pk_fma(wlo[MT], pk_mul(elo, vlo), num2);                   \
        num2 = pk_fma(whi[MT], pk_mul(ehi, vhi), num2);                   \
      }
      EPAIRS(0)
      EPAIRS(1)
      EPAIRS(2)
      if (wm == 0) EPAIRS(3)   // wave-uniform; static acc[3][nt]
      #undef EPAIRS

      float den = den2[0] + den2[1];
      float num = num2[0] + num2[1];
      den += __shfl_xor(den, 16, 64);
      den += __shfl_xor(den, 32, 64);
      num += __shfl_xor(num, 16, 64);
      num += __shfl_xor(num, 32, 64);
      const int col = wn * 32 + nt * 16 + l15;
      if (quad == 0) {
        sDen[buf][wm][col] = den;
        sNum[buf][wm][col] = num;
      }
      // row 100 = wm1, mt2, quad1, r0
      if (wm == 1 && quad == 1) sDir[buf][col] = acc[2][nt][0];
    }
  }

  __syncthreads();

  // ---- combine final stage (ps=7, parity 1, it=3) ----
  if (t < BN) {
    float den = sDen[1][0][t] + sDen[1][1][t];
    float num = sNum[1][0][t] + sNum[1][1][t];
    const float dir = sDir[1][t];
    const float dirE = fexp2(dir * L2E);
    den -= 11.f + dirE;
    const float val = num * __builtin_amdgcn_rcpf(den) + dir;
    const int v = v0 + t;
    if (v < VDIM) out[(size_t)(bg4 + 3) * VDIM + v] = sRes[3][t] + val;
  }
}

extern "C" void kernel_launch(void* const* d_in, const int* in_sizes, int n_in,
                              void* d_out, int out_size, void* d_ws, size_t ws_size,
                              hipStream_t stream) {
  const int*   attr_item = (const int*)d_in[0];
  const float* tf_item   = (const float*)d_in[1];
  const int*   lens_item = (const int*)d_in[2];
  const int*   item_ids  = (const int*)d_in[3];
  const int*   attr_user = (const int*)d_in[4];
  const float* tf_user   = (const float*)d_in[5];
  const int*   lens_user = (const int*)d_in[6];
  const int*   user_ids  = (const int*)d_in[7];
  const float* W_item    = (const float*)d_in[8];
  const float* W_user    = (const float*)d_in[9];
  const float* user_emb  = (const float*)d_in[10];
  const float* item_emb  = (const float*)d_in[11];
  float* out = (float*)d_out;

  unsigned short* wbf = (unsigned short*)d_ws;                  // [2][V][E] bf16 (linear)
  unsigned short* abf = wbf + (size_t)2 * VDIM * EDIM;          // [2][64] swizzled 28KB tiles

  prep_kernel<<<dim3(2500 + 128), 256, 0, stream>>>(W_item, W_user, attr_item, attr_user,
                                                    item_ids, user_ids, item_emb, user_emb,
                                                    wbf, abf);
  main_kernel<<<dim3(GRID), 512, 0, stream>>>(wbf, abf, tf_item, lens_item,
                                              tf_user, lens_user, out);
}